// Round 7
// baseline (685.497 us; speedup 1.0000x reference)
//
#include <hip/hip_runtime.h>
#include <hip/hip_bf16.h>
#include <cmath>

// Problem dims (fixed): B=16, T=1024, IN=1024, H=1024
// M = B*T = 16384, K1 = 1024, N1 = 1024, K2 = 2048, N2 = 1024
//
// Numerics contract (validated round 5): GEMM1 must be a sequential
// ascending-k f32 FMA chain per output element + separate f32 bias add
// (mirrors the np golden's BLAS sgemm). Scan mirrors numpy f32 op-for-op.
// GEMM2 (smooth tanh) is bf16 MFMA.
//
// Round 7: gemm1 staging -> m97 structure: global_load_lds width=16 into a
// linear [128][32] f32 LDS tile (2-barrier K-loop), with T21-correct granule
// XOR swizzle (linear LDS dest + pre-swizzled global source + swizzled read)
// to kill the 128B-row bank conflicts. FMA chain order unchanged.

typedef __attribute__((ext_vector_type(8))) __bf16 bf16x8;
typedef __attribute__((ext_vector_type(4))) __bf16 bf16x4;
typedef __attribute__((ext_vector_type(4))) float  f32x4;

typedef const void __attribute__((address_space(1)))* gas_cp;
typedef void __attribute__((address_space(3)))*       las_p;

#define LDT 40  // bf16 LDS pad (GEMM2)

// ---------------------------------------------------------------------------
// GEMM1 (f32 FMA-chain): I[m,h] = fadd( fmaf-chain_{k=0..1023}, b_in[h] )
// ---------------------------------------------------------------------------
__global__ __launch_bounds__(256)
void gemm1_f32chain_kernel(const float* __restrict__ X,
                           const float* __restrict__ W,
                           const float* __restrict__ bias,
                           float* __restrict__ I)
{
    // linear [128][32] f32 tiles (4KB rows of 128B); 16KB each
    __shared__ __align__(16) float sA[128 * 32];
    __shared__ __align__(16) float sB[128 * 32];

    const int tid  = threadIdx.x;
    const int bn   = blockIdx.x;      // 0..7
    const int bm   = blockIdx.y;      // 0..127
    const int row0 = bm * 128;
    const int col0 = bn * 128;
    const int tx   = tid & 15;
    const int ty   = tid >> 4;
    const int w    = tid >> 6;        // wave id 0..3
    const int l    = tid & 63;        // lane

    // staging geometry: per wave-issue, 64 lanes x 16B = 8 rows of 128B.
    const int srow = l >> 3;                 // row within 8-row chunk (== row&7)
    const int sgr  = (l & 7) ^ srow;         // pre-swizzled SOURCE granule
    // read-side swizzle keys (row&7 is constant per thread: 16i ≡ 0 mod 8)
    const int tya  = ty & 7;
    const int txb  = tx & 7;

    float acc[8][8];
    #pragma unroll
    for (int i = 0; i < 8; ++i)
        #pragma unroll
        for (int j = 0; j < 8; ++j)
            acc[i][j] = 0.0f;

    for (int k0 = 0; k0 < 1024; k0 += 32) {
        // stage: global_load_lds, 4 issues per wave per matrix.
        // LDS[row][g] receives source granule g^(row&7); reads undo the XOR.
        #pragma unroll
        for (int i = 0; i < 4; ++i) {
            const int rb = w * 32 + i * 8;   // wave-uniform row base
            const float* ga = &X[(size_t)(row0 + rb + srow) * 1024 + k0 + (sgr << 2)];
            const float* gb = &W[(size_t)(col0 + rb + srow) * 1024 + k0 + (sgr << 2)];
            __builtin_amdgcn_global_load_lds((gas_cp)ga, (las_p)&sA[rb * 32], 16, 0, 0);
            __builtin_amdgcn_global_load_lds((gas_cp)gb, (las_p)&sB[rb * 32], 16, 0, 0);
        }
        __syncthreads();  // drains vmcnt(0) then barrier (compiler-emitted)

        // compute: FMA order strictly ascending k (kk group asc, q asc)
        #pragma unroll
        for (int kk = 0; kk < 32; kk += 4) {
            const int G = kk >> 2;
            f32x4 a4[8], b4[8];
            #pragma unroll
            for (int i = 0; i < 8; ++i)
                a4[i] = *(const f32x4*)&sA[(ty + 16 * i) * 32 + ((G ^ tya) << 2)];
            #pragma unroll
            for (int j = 0; j < 8; ++j)
                b4[j] = *(const f32x4*)&sB[(tx + 16 * j) * 32 + ((G ^ txb) << 2)];
            #pragma unroll
            for (int q = 0; q < 4; ++q)
                #pragma unroll
                for (int i = 0; i < 8; ++i)
                    #pragma unroll
                    for (int j = 0; j < 8; ++j)
                        acc[i][j] = fmaf(a4[i][q], b4[j][q], acc[i][j]);
        }
        __syncthreads();  // protect LDS before next stage overwrites
    }

    #pragma unroll
    for (int i = 0; i < 8; ++i)
        #pragma unroll
        for (int j = 0; j < 8; ++j) {
            int rg = row0 + ty + 16 * i;
            int cg = col0 + tx + 16 * j;
            I[(size_t)rg * 1024 + cg] = __fadd_rn(acc[i][j], bias[cg]);
        }
}

// ---------------------------------------------------------------------------
// Scan, numpy-f32 mirror (validated):
//   alpha = expf(-logaddexpf(lt,0)) via round-to-f32 of f64 libm
//   v = fadd(fmul(alpha, v), I); spike = v > thr; v = fmul(v, 1-spike)
// ---------------------------------------------------------------------------
__global__ void hsru_scan_f32_kernel(const float* __restrict__ I,
                                     const float* __restrict__ leak,
                                     const float* __restrict__ thr,
                                     __bf16* __restrict__ comb)
{
    int g = blockIdx.x * blockDim.x + threadIdx.x;  // 0..16383
    int b = g >> 10;
    int h = g & 1023;

    float lt = leak[h];
    float e     = (float)exp(-(double)fabsf(lt));
    float l1    = (float)log1p((double)e);
    float sp    = __fadd_rn(fmaxf(lt, 0.0f), l1);
    float alpha = (float)exp(-(double)sp);
    float th    = thr[h];

    const float* Ip = I    + (size_t)b * (1024 * 1024) + h;
    __bf16*      cp = comb + (size_t)b * (1024 * 2048) + h;

    float v = 0.0f;
    #pragma unroll 4
    for (int t = 0; t < 1024; ++t) {
        float cur = Ip[(size_t)t * 1024];
        v = __fadd_rn(__fmul_rn(alpha, v), cur);
        float spike = (v > th) ? 1.0f : 0.0f;
        v = __fmul_rn(v, __fsub_rn(1.0f, spike));
        cp[(size_t)t * 2048]        = (__bf16)v;
        cp[(size_t)t * 2048 + 1024] = (__bf16)spike;
    }
}

// ---------------------------------------------------------------------------
// GEMM2: out = tanh(combined @ W_out^T + b_out), bf16 MFMA (smooth path).
// ---------------------------------------------------------------------------
__global__ __launch_bounds__(256)
void gemm2_kernel(const __bf16* __restrict__ A,
                  const float* __restrict__ W,
                  const float* __restrict__ bias,
                  float* __restrict__ O)
{
    __shared__ __align__(16) __bf16 sA[128][LDT];
    __shared__ __align__(16) __bf16 sB[128][LDT];

    const int tid  = threadIdx.x;
    const int bn   = blockIdx.x;
    const int bm   = blockIdx.y;
    const int row0 = bm * 128;
    const int col0 = bn * 128;

    const int lane = tid & 63;
    const int wid  = tid >> 6;
    const int wm   = (wid >> 1) * 64;
    const int wn   = (wid & 1) * 64;

    f32x4 acc[4][4];
    #pragma unroll
    for (int i = 0; i < 4; ++i)
        #pragma unroll
        for (int j = 0; j < 4; ++j)
            acc[i][j] = f32x4{0.f, 0.f, 0.f, 0.f};

    const int frow  = lane & 15;
    const int fkoff = (lane >> 4) * 8;

    for (int k0 = 0; k0 < 2048; k0 += 32) {
        #pragma unroll
        for (int i = 0; i < 2; ++i) {
            int q  = tid + i * 256;
            int r  = q >> 2;
            int c8 = (q & 3) * 8;
            *(bf16x8*)&sA[r][c8] = *(const bf16x8*)&A[(size_t)(row0 + r) * 2048 + k0 + c8];
        }
        #pragma unroll
        for (int i = 0; i < 4; ++i) {
            int q  = tid + i * 256;
            int r  = q >> 3;
            int c4 = (q & 7) * 4;
            const f32x4 vb = *(const f32x4*)&W[(size_t)(col0 + r) * 2048 + k0 + c4];
            bf16x4 bh;
            #pragma unroll
            for (int j = 0; j < 4; ++j) bh[j] = (__bf16)vb[j];
            *(bf16x4*)&sB[r][c4] = bh;
        }
        __syncthreads();

        bf16x8 a_f[4], b_f[4];
        #pragma unroll
        for (int f = 0; f < 4; ++f) {
            a_f[f] = *(const bf16x8*)&sA[wm + f * 16 + frow][fkoff];
            b_f[f] = *(const bf16x8*)&sB[wn + f * 16 + frow][fkoff];
        }
        #pragma unroll
        for (int fm = 0; fm < 4; ++fm)
            #pragma unroll
            for (int fn = 0; fn < 4; ++fn)
                acc[fm][fn] = __builtin_amdgcn_mfma_f32_16x16x32_bf16(a_f[fm], b_f[fn], acc[fm][fn], 0, 0, 0);
        __syncthreads();
    }

    const int crow = (lane >> 4) * 4;
    const int ccol = lane & 15;
    #pragma unroll
    for (int fm = 0; fm < 4; ++fm)
        #pragma unroll
        for (int fn = 0; fn < 4; ++fn)
            #pragma unroll
            for (int j = 0; j < 4; ++j) {
                int rg = row0 + wm + fm * 16 + crow + j;
                int cg = col0 + wn + fn * 16 + ccol;
                O[(size_t)rg * 1024 + cg] = tanhf(acc[fm][fn][j] + bias[cg]);
            }
}

// ---------------------------------------------------------------------------
extern "C" void kernel_launch(void* const* d_in, const int* in_sizes, int n_in,
                              void* d_out, int out_size, void* d_ws, size_t ws_size,
                              hipStream_t stream)
{
    const float* x     = (const float*)d_in[0];
    const float* W_in  = (const float*)d_in[1];
    const float* b_in  = (const float*)d_in[2];
    const float* leak  = (const float*)d_in[3];
    const float* thr   = (const float*)d_in[4];
    const float* W_out = (const float*)d_in[5];
    const float* b_out = (const float*)d_in[6];

    const size_t NEED = 64ull * 1024 * 1024;  // comb bf16 [16,1024,2048]
    if (ws_size < NEED) return;

    float*  out  = (float*)d_out;   // also I scratch
    __bf16* comb = (__bf16*)d_ws;

    dim3 grid(8, 128);

    gemm1_f32chain_kernel<<<grid, 256, 0, stream>>>(x, W_in, b_in, out);
    hsru_scan_f32_kernel<<<64, 256, 0, stream>>>(out, leak, thr, comb);
    gemm2_kernel<<<grid, 256, 0, stream>>>(comb, W_out, b_out, out);
}

// Round 8
// 663.047 us; speedup vs baseline: 1.0339x; 1.0339x over previous
//
#include <hip/hip_runtime.h>
#include <hip/hip_bf16.h>
#include <cmath>

// Problem dims (fixed): B=16, T=1024, IN=1024, H=1024
// M = B*T = 16384, K1 = 1024, N1 = 1024, K2 = 2048, N2 = 1024
//
// Numerics contract (validated round 5): GEMM1 must be a sequential
// ascending-k f32 FMA chain per output element + separate f32 bias add
// (mirrors the np golden's BLAS sgemm). Scan mirrors numpy f32 op-for-op.
// GEMM2 (smooth tanh) is bf16 MFMA.
//
// Round 8: revert gemm1 LDS to the measured-conflict-free padded layout
// (round 6: LDF=36, 0 conflicts) and add REGISTER DOUBLE-BUFFERING: global
// loads for tile k+1 issue right after the LDS-ready barrier and complete
// under the 4096-cycle FMA phase (T14 regime: compute >> HBM latency).
// gemm2: W_out pre-converted to bf16 once (ws), halving B staging work.

typedef __attribute__((ext_vector_type(8))) __bf16 bf16x8;
typedef __attribute__((ext_vector_type(4))) __bf16 bf16x4;
typedef __attribute__((ext_vector_type(4))) float  f32x4;

#define LDT 40  // bf16 LDS pad (GEMM2): 80B rows
#define LDF 36  // f32 LDS pad (GEMM1): 144B rows — measured 0 bank conflicts

// ---------------------------------------------------------------------------
// GEMM1 (f32 FMA-chain): I[m,h] = fadd( fmaf-chain_{k=0..1023}, b_in[h] )
// reg-dbuf: LOAD(k+1) issues after LDS-ready barrier, drains under FMAs.
// ---------------------------------------------------------------------------
__global__ __launch_bounds__(256)
void gemm1_f32chain_kernel(const float* __restrict__ X,
                           const float* __restrict__ W,
                           const float* __restrict__ bias,
                           float* __restrict__ I)
{
    __shared__ __align__(16) float sA[128][LDF];
    __shared__ __align__(16) float sB[128][LDF];

    const int tid  = threadIdx.x;
    const int bn   = blockIdx.x;      // 0..7
    const int bm   = blockIdx.y;      // 0..127
    const int row0 = bm * 128;
    const int col0 = bn * 128;
    const int tx   = tid & 15;
    const int ty   = tid >> 4;

    // staging geometry (4 float4 chunks per matrix per thread)
    int rr[4], cc[4];
    #pragma unroll
    for (int i = 0; i < 4; ++i) {
        int q = tid + i * 256;        // 0..1023
        rr[i] = q >> 3;               // row 0..127
        cc[i] = (q & 7) * 4;          // col 0..28
    }

    f32x4 av[4], bv[4];               // in-flight tile registers

    float acc[8][8];
    #pragma unroll
    for (int i = 0; i < 8; ++i)
        #pragma unroll
        for (int j = 0; j < 8; ++j)
            acc[i][j] = 0.0f;

    // prologue: load tile 0 into regs
    #pragma unroll
    for (int i = 0; i < 4; ++i) {
        av[i] = *(const f32x4*)&X[(size_t)(row0 + rr[i]) * 1024 + cc[i]];
        bv[i] = *(const f32x4*)&W[(size_t)(col0 + rr[i]) * 1024 + cc[i]];
    }

    for (int k0 = 0; k0 < 1024; k0 += 32) {
        __syncthreads();              // consumers of previous tile done
        #pragma unroll
        for (int i = 0; i < 4; ++i) {
            *(f32x4*)&sA[rr[i]][cc[i]] = av[i];
            *(f32x4*)&sB[rr[i]][cc[i]] = bv[i];
        }
        __syncthreads();              // LDS tile ready

        if (k0 + 32 < 1024) {
            const int kn = k0 + 32;   // issue next-tile loads; drain under FMAs
            #pragma unroll
            for (int i = 0; i < 4; ++i) {
                av[i] = *(const f32x4*)&X[(size_t)(row0 + rr[i]) * 1024 + kn + cc[i]];
                bv[i] = *(const f32x4*)&W[(size_t)(col0 + rr[i]) * 1024 + kn + cc[i]];
            }
        }

        // compute: FMA order strictly ascending k (kk group asc, q asc)
        #pragma unroll
        for (int kk = 0; kk < 32; kk += 4) {
            f32x4 a4[8], b4[8];
            #pragma unroll
            for (int i = 0; i < 8; ++i) a4[i] = *(const f32x4*)&sA[ty + 16 * i][kk];
            #pragma unroll
            for (int j = 0; j < 8; ++j) b4[j] = *(const f32x4*)&sB[tx + 16 * j][kk];
            #pragma unroll
            for (int q = 0; q < 4; ++q)
                #pragma unroll
                for (int i = 0; i < 8; ++i)
                    #pragma unroll
                    for (int j = 0; j < 8; ++j)
                        acc[i][j] = fmaf(a4[i][q], b4[j][q], acc[i][j]);
        }
    }

    #pragma unroll
    for (int i = 0; i < 8; ++i)
        #pragma unroll
        for (int j = 0; j < 8; ++j) {
            int rg = row0 + ty + 16 * i;
            int cg = col0 + tx + 16 * j;
            I[(size_t)rg * 1024 + cg] = __fadd_rn(acc[i][j], bias[cg]);
        }
}

// ---------------------------------------------------------------------------
// Scan, numpy-f32 mirror (validated):
//   alpha = expf(-logaddexpf(lt,0)) via round-to-f32 of f64 libm
//   v = fadd(fmul(alpha, v), I); spike = v > thr; v = fmul(v, 1-spike)
// ---------------------------------------------------------------------------
__global__ void hsru_scan_f32_kernel(const float* __restrict__ I,
                                     const float* __restrict__ leak,
                                     const float* __restrict__ thr,
                                     __bf16* __restrict__ comb)
{
    int g = blockIdx.x * blockDim.x + threadIdx.x;  // 0..16383
    int b = g >> 10;
    int h = g & 1023;

    float lt = leak[h];
    float e     = (float)exp(-(double)fabsf(lt));
    float l1    = (float)log1p((double)e);
    float sp    = __fadd_rn(fmaxf(lt, 0.0f), l1);
    float alpha = (float)exp(-(double)sp);
    float th    = thr[h];

    const float* Ip = I    + (size_t)b * (1024 * 1024) + h;
    __bf16*      cp = comb + (size_t)b * (1024 * 2048) + h;

    float v = 0.0f;
    #pragma unroll 4
    for (int t = 0; t < 1024; ++t) {
        float cur = Ip[(size_t)t * 1024];
        v = __fadd_rn(__fmul_rn(alpha, v), cur);
        float spike = (v > th) ? 1.0f : 0.0f;
        v = __fmul_rn(v, __fsub_rn(1.0f, spike));
        cp[(size_t)t * 2048]        = (__bf16)v;
        cp[(size_t)t * 2048 + 1024] = (__bf16)spike;
    }
}

// ---------------------------------------------------------------------------
// W_out f32 -> bf16 pre-convert (once per launch; 2M elements)
// ---------------------------------------------------------------------------
__global__ __launch_bounds__(256)
void wcvt_kernel(const float* __restrict__ W, __bf16* __restrict__ Wb)
{
    int idx = (blockIdx.x * 256 + threadIdx.x) * 8;   // 8 elements/thread
    f32x4 v0 = *(const f32x4*)&W[idx];
    f32x4 v1 = *(const f32x4*)&W[idx + 4];
    bf16x8 o;
    #pragma unroll
    for (int j = 0; j < 4; ++j) { o[j] = (__bf16)v0[j]; o[4 + j] = (__bf16)v1[j]; }
    *(bf16x8*)&Wb[idx] = o;
}

// ---------------------------------------------------------------------------
// GEMM2: out = tanh(combined @ Wb^T + b_out), bf16 MFMA (smooth path).
// A = comb [M,2048] bf16, B = Wb [1024,2048] bf16 (pre-converted)
// ---------------------------------------------------------------------------
__global__ __launch_bounds__(256)
void gemm2_kernel(const __bf16* __restrict__ A,
                  const __bf16* __restrict__ Wb,
                  const float* __restrict__ bias,
                  float* __restrict__ O)
{
    __shared__ __align__(16) __bf16 sA[128][LDT];
    __shared__ __align__(16) __bf16 sB[128][LDT];

    const int tid  = threadIdx.x;
    const int bn   = blockIdx.x;
    const int bm   = blockIdx.y;
    const int row0 = bm * 128;
    const int col0 = bn * 128;

    const int lane = tid & 63;
    const int wid  = tid >> 6;
    const int wm   = (wid >> 1) * 64;
    const int wn   = (wid & 1) * 64;

    f32x4 acc[4][4];
    #pragma unroll
    for (int i = 0; i < 4; ++i)
        #pragma unroll
        for (int j = 0; j < 4; ++j)
            acc[i][j] = f32x4{0.f, 0.f, 0.f, 0.f};

    const int frow  = lane & 15;
    const int fkoff = (lane >> 4) * 8;

    for (int k0 = 0; k0 < 2048; k0 += 32) {
        #pragma unroll
        for (int i = 0; i < 2; ++i) {
            int q  = tid + i * 256;   // 0..511
            int r  = q >> 2;          // 0..127
            int c8 = (q & 3) * 8;     // 0..24
            *(bf16x8*)&sA[r][c8] = *(const bf16x8*)&A [(size_t)(row0 + r) * 2048 + k0 + c8];
            *(bf16x8*)&sB[r][c8] = *(const bf16x8*)&Wb[(size_t)(col0 + r) * 2048 + k0 + c8];
        }
        __syncthreads();

        bf16x8 a_f[4], b_f[4];
        #pragma unroll
        for (int f = 0; f < 4; ++f) {
            a_f[f] = *(const bf16x8*)&sA[wm + f * 16 + frow][fkoff];
            b_f[f] = *(const bf16x8*)&sB[wn + f * 16 + frow][fkoff];
        }
        #pragma unroll
        for (int fm = 0; fm < 4; ++fm)
            #pragma unroll
            for (int fn = 0; fn < 4; ++fn)
                acc[fm][fn] = __builtin_amdgcn_mfma_f32_16x16x32_bf16(a_f[fm], b_f[fn], acc[fm][fn], 0, 0, 0);
        __syncthreads();
    }

    const int crow = (lane >> 4) * 4;
    const int ccol = lane & 15;
    #pragma unroll
    for (int fm = 0; fm < 4; ++fm)
        #pragma unroll
        for (int fn = 0; fn < 4; ++fn)
            #pragma unroll
            for (int j = 0; j < 4; ++j) {
                int rg = row0 + wm + fm * 16 + crow + j;
                int cg = col0 + wn + fn * 16 + ccol;
                O[(size_t)rg * 1024 + cg] = tanhf(acc[fm][fn][j] + bias[cg]);
            }
}

// ---------------------------------------------------------------------------
extern "C" void kernel_launch(void* const* d_in, const int* in_sizes, int n_in,
                              void* d_out, int out_size, void* d_ws, size_t ws_size,
                              hipStream_t stream)
{
    const float* x     = (const float*)d_in[0];
    const float* W_in  = (const float*)d_in[1];
    const float* b_in  = (const float*)d_in[2];
    const float* leak  = (const float*)d_in[3];
    const float* thr   = (const float*)d_in[4];
    const float* W_out = (const float*)d_in[5];
    const float* b_out = (const float*)d_in[6];

    // ws: [0,64MiB) comb bf16 ; [64MiB, 64MiB+4MiB) Wb bf16
    const size_t NEED = (64ull << 20) + (4ull << 20);
    if (ws_size < NEED) return;   // (round 3 proved ws >= 96 MiB)

    float*  out  = (float*)d_out;   // also I scratch
    __bf16* comb = (__bf16*)d_ws;
    __bf16* Wb   = (__bf16*)((char*)d_ws + (64ull << 20));

    dim3 grid(8, 128);

    wcvt_kernel<<<1024, 256, 0, stream>>>(W_out, Wb);   // 2M elems / 8 per thread
    gemm1_f32chain_kernel<<<grid, 256, 0, stream>>>(x, W_in, b_in, out);
    hsru_scan_f32_kernel<<<64, 256, 0, stream>>>(out, leak, thr, comb);
    gemm2_kernel<<<grid, 256, 0, stream>>>(comb, Wb, b_out, out);
}